// Round 2
// baseline (815.871 us; speedup 1.0000x reference)
//
#include <hip/hip_runtime.h>
#include <math.h>

#define BB 256
#define TT 1024
#define KK 128
#define CHUNK 8
#define NCHUNK (TT / CHUNK)  // 128

__global__ void zero_out_kernel(float* out) { out[0] = 0.0f; }

// One block per batch. 256 threads: j = tid>>1 (output state), q = tid&1 (i-half).
// Forward algorithm in "exp space": p[i] = exp(alpha[i]-m) in LDS, E=exp(Trans)
// in registers, z[j] = sum_i p[i]*E[i][j] via 64 fp32 FMAs/thread/step.
__global__ __launch_bounds__(256) void crf_kernel(
    const float* __restrict__ inputs,      // B*T*K fp32
    const float* __restrict__ trans,       // K*K fp32
    const int* __restrict__ tags,          // B*T int32 (harness casts int64 -> int32)
    const int* __restrict__ mask,          // B*T int32
    float* __restrict__ out)               // scalar
{
    __shared__ __align__(16) float pbuf[2][KK];
    __shared__ __align__(16) float ebuf[2][CHUNK * KK];
    __shared__ float mbuf[2][CHUNK];
    __shared__ float m_slot;
    __shared__ float scratch[8];

    const int tid = threadIdx.x;
    const int q   = tid & 1;
    const int j   = tid >> 1;
    const int b   = blockIdx.x;

    const float* binp  = inputs + (size_t)b * TT * KK;
    const int* bmask   = mask + (size_t)b * TT;
    const int* btags   = tags + (size_t)b * TT;

    // E fragment in registers: i = q*64 + ii  ->  E[ii] = exp(trans[i][j])
    float Ereg[64];
#pragma unroll
    for (int ii = 0; ii < 64; ++ii)
        Ereg[ii] = expf(trans[(q * 64 + ii) * KK + j]);

    // stage chunk 0 of emissions (t=0..7) + mask
    ((float4*)ebuf[0])[tid] = ((const float4*)binp)[tid];
    if (tid < CHUNK) mbuf[0][tid] = (float)bmask[tid];
    __syncthreads();

    // t = 0: alpha0 = emit[0]
    float a   = ebuf[0][j];
    float m_c = 0.0f;
    if (q == 0) pbuf[0][j] = __expf(a);
    __syncthreads();

    for (int c = 0; c < NCHUNK; ++c) {
        // prefetch next emission chunk into registers
        float4 epre; int mpre = 0;
        if (c + 1 < NCHUNK) {
            epre = ((const float4*)(binp + (size_t)(c + 1) * CHUNK * KK))[tid];
            if (tid < CHUNK) mpre = bmask[(c + 1) * CHUNK + tid];
        }
        const float* eb = ebuf[c & 1];
        const float* mb = mbuf[c & 1];
        const int s0 = (c == 0) ? 1 : 0;
        for (int s = s0; s < CHUNK; ++s) {
            const int t = c * CHUNK + s;
            const float* pr = pbuf[(t - 1) & 1] + (q << 6);
            float z0 = 0.f, z1 = 0.f, z2 = 0.f, z3 = 0.f;
#pragma unroll
            for (int c4 = 0; c4 < 16; ++c4) {
                float4 pv = ((const float4*)pr)[c4];
                z0 = fmaf(pv.x, Ereg[4 * c4 + 0], z0);
                z1 = fmaf(pv.y, Ereg[4 * c4 + 1], z1);
                z2 = fmaf(pv.z, Ereg[4 * c4 + 2], z2);
                z3 = fmaf(pv.w, Ereg[4 * c4 + 3], z3);
            }
            float z = (z0 + z1) + (z2 + z3);
            z += __shfl_xor(z, 1);                 // pair-combine the two i-halves
            float anew = m_c + __logf(z) + eb[s * KK + j];
            float mi   = mb[s];
            a = mi * anew + (1.0f - mi) * a;       // mask update (all-ones in test)
            // renorm every CHUNK steps with lagged alpha[0] (written at s==CHUNK-2)
            float m_n = (s == CHUNK - 1) ? m_slot : m_c;
            float pnew = __expf(a - m_n);
            m_c = m_n;
            if (q == 0) pbuf[t & 1][j] = pnew;
            if (tid == 0 && s == CHUNK - 2) m_slot = a;
            __syncthreads();                        // pbuf[t&1] + m_slot visible
        }
        if (c + 1 < NCHUNK) {
            ((float4*)ebuf[(c + 1) & 1])[tid] = epre;
            if (tid < CHUNK) mbuf[(c + 1) & 1][tid] = (float)mpre;
            __syncthreads();
        }
    }

    // ---- denominator: LSE_j(a). Every j is held by 2 threads -> halve the sum.
    float v = a;
#pragma unroll
    for (int o = 1; o < 64; o <<= 1) v = fmaxf(v, __shfl_xor(v, o));
    if ((tid & 63) == 0) scratch[tid >> 6] = v;
    __syncthreads();
    float mx = fmaxf(fmaxf(scratch[0], scratch[1]), fmaxf(scratch[2], scratch[3]));
    float ev = __expf(a - mx);
#pragma unroll
    for (int o = 1; o < 64; o <<= 1) ev += __shfl_xor(ev, o);
    __syncthreads();
    if ((tid & 63) == 0) scratch[tid >> 6] = ev;
    __syncthreads();
    float den = mx + __logf(0.5f * ((scratch[0] + scratch[1]) + (scratch[2] + scratch[3])));

    // ---- numerator (gold-path score) ----
    float numpart = 0.0f, maskpart = 0.0f;
#pragma unroll
    for (int kk = 0; kk < TT / 256; ++kk) {
        int t = tid + 256 * kk;
        int tg = btags[t];
        float mf = (float)bmask[t];
        maskpart += mf;
        if (t < TT - 1) {
            int tg1   = btags[t + 1];
            float mf1 = (float)bmask[t + 1];
            numpart += trans[tg * KK + tg1] * mf1;
            numpart += binp[(size_t)t * KK + tg] * mf;
        }
    }
#pragma unroll
    for (int o = 1; o < 64; o <<= 1) numpart += __shfl_xor(numpart, o);
#pragma unroll
    for (int o = 1; o < 64; o <<= 1) maskpart += __shfl_xor(maskpart, o);
    __syncthreads();
    if ((tid & 63) == 0) {
        scratch[tid >> 6]       = numpart;
        scratch[4 + (tid >> 6)] = maskpart;
    }
    __syncthreads();
    if (tid == 0) {
        float num  = (scratch[0] + scratch[1]) + (scratch[2] + scratch[3]);
        float msum = (scratch[4] + scratch[5]) + (scratch[6] + scratch[7]);
        int last_idx = (int)msum - 1;
        int ltag = btags[last_idx];
        num += binp[(size_t)(TT - 1) * KK + ltag] * (float)bmask[TT - 1];
        atomicAdd(out, num - den);
    }
}

extern "C" void kernel_launch(void* const* d_in, const int* in_sizes, int n_in,
                              void* d_out, int out_size, void* d_ws, size_t ws_size,
                              hipStream_t stream) {
    const float* inputs = (const float*)d_in[0];
    const float* trans  = (const float*)d_in[1];
    const int* tagsp    = (const int*)d_in[2];
    const int* maskp    = (const int*)d_in[3];
    float* out          = (float*)d_out;
    zero_out_kernel<<<1, 1, 0, stream>>>(out);
    crf_kernel<<<BB, 256, 0, stream>>>(inputs, trans, tagsp, maskp, out);
}

// Round 3
// 720.684 us; speedup vs baseline: 1.1321x; 1.1321x over previous
//
#include <hip/hip_runtime.h>
#include <math.h>

#define BB 256
#define TT 1024
#define KK 128
#define CHUNK 8
#define NCHUNK (TT / CHUNK)  // 128
#define PHALF 80             // padded half stride: 64 data + 16 pad floats
#define PIDX(i) ((i) + (((i) >> 6) << 4))

__global__ void zero_out_kernel(float* out) { out[0] = 0.0f; }

// One block per batch. 256 threads: j = tid>>1 (output state), q = tid&1 (i-half).
// Forward recursion fully in exp space: p[i] = exp(alpha[i] - m) in LDS,
// E = exp(Trans) in registers (16 float4/thread), X = exp(emit) staged in LDS.
// Step: z[j] = sum_i p[i]*E[i][j];  p'[j] = z[j]*X[t][j] * 2^-E0,
// where E0 = exponent(p_prev[0]) (wave-uniform broadcast value, exact pow2).
// No log/exp in the step loop; m tracked as integer bit count.
__global__ __launch_bounds__(256, 1) void crf_kernel(
    const float* __restrict__ inputs,      // B*T*K fp32
    const float* __restrict__ trans,       // K*K fp32
    const int* __restrict__ tags,          // B*T (int64 stored, read low words via harness int32 view)
    const int* __restrict__ mask,          // B*T int32
    float* __restrict__ out)               // scalar
{
    __shared__ __align__(16) float pbuf[2][2 * PHALF];
    __shared__ __align__(16) float ebuf[2][CHUNK * KK];   // holds exp(e)
    __shared__ float mbuf[2][CHUNK];
    __shared__ float scratch[8];

    const int tid = threadIdx.x;
    const int q   = tid & 1;
    const int j   = tid >> 1;
    const int b   = blockIdx.x;

    const float* binp = inputs + (size_t)b * TT * KK;
    const int* bmask  = mask + (size_t)b * TT;
    const int* btags  = tags + (size_t)b * TT;

    // E fragment in registers: i = q*64 + 4*c4 + e  ->  exp(trans[i][j])
    float4 E[16];
#pragma unroll
    for (int c4 = 0; c4 < 16; ++c4) {
        const float* tp = trans + (size_t)(q * 64 + 4 * c4) * KK + j;
        E[c4].x = expf(tp[0 * KK]);
        E[c4].y = expf(tp[1 * KK]);
        E[c4].z = expf(tp[2 * KK]);
        E[c4].w = expf(tp[3 * KK]);
    }

    // stage chunk 0 of emissions as X = exp(e), + mask
    {
        float4 e4 = ((const float4*)binp)[tid];
        e4.x = __expf(e4.x); e4.y = __expf(e4.y);
        e4.z = __expf(e4.z); e4.w = __expf(e4.w);
        ((float4*)ebuf[0])[tid] = e4;
    }
    if (tid < CHUNK) mbuf[0][tid] = (float)bmask[tid];
    __syncthreads();

    // t = 0: alpha0 = emit[0]  ->  p = exp(alpha0) = X[0][j], m = 0
    float pcur = ebuf[0][j];
    int m_int = 0;
    if (q == 0) pbuf[0][PIDX(j)] = pcur;
    __syncthreads();

    for (int c = 0; c < NCHUNK; ++c) {
        // prefetch next emission chunk into registers (raw e; exp applied at store)
        float4 epre; int mpre = 0;
        if (c + 1 < NCHUNK) {
            epre = ((const float4*)(binp + (size_t)(c + 1) * CHUNK * KK))[tid];
            if (tid < CHUNK) mpre = bmask[(c + 1) * CHUNK + tid];
        }
        const float* eb = ebuf[c & 1];
        const float* mb = mbuf[c & 1];
        const int s0 = (c == 0) ? 1 : 0;
        for (int s = s0; s < CHUNK; ++s) {
            const int t = c * CHUNK + s;
            const float* pr = pbuf[(t - 1) & 1] + q * PHALF;
            float4 pv0 = ((const float4*)pr)[0];
            float z0 = pv0.x * E[0].x;
            float z1 = pv0.y * E[0].y;
            float z2 = pv0.z * E[0].z;
            float z3 = pv0.w * E[0].w;
#pragma unroll
            for (int c4 = 1; c4 < 16; ++c4) {
                float4 pv = ((const float4*)pr)[c4];
                z0 = fmaf(pv.x, E[c4].x, z0);
                z1 = fmaf(pv.y, E[c4].y, z1);
                z2 = fmaf(pv.z, E[c4].z, z2);
                z3 = fmaf(pv.w, E[c4].w, z3);
            }
            float z = (z0 + z1) + (z2 + z3);
            z += __shfl_xor(z, 1);                 // combine the two i-halves
            float X  = eb[s * KK + j];
            float mi = mb[s];
            float pn = (mi != 0.0f) ? z * X : pcur;   // mask-hold (exact, mi in {0,1})
            // wave-uniform renorm: E0 = exponent of p_prev[0] (q0's pv0.x)
            int E0 = (int)((__float_as_uint(pv0.x) >> 23) & 255u) - 127;
            float sc = __uint_as_float((unsigned)(127 - E0) << 23);   // 2^-E0
            pcur = pn * sc;
            m_int += E0;
            if (q == 0) pbuf[t & 1][PIDX(j)] = pcur;
            __syncthreads();
        }
        if (c + 1 < NCHUNK) {
            epre.x = __expf(epre.x); epre.y = __expf(epre.y);
            epre.z = __expf(epre.z); epre.w = __expf(epre.w);
            ((float4*)ebuf[(c + 1) & 1])[tid] = epre;
            if (tid < CHUNK) mbuf[(c + 1) & 1][tid] = (float)mpre;
            __syncthreads();
        }
    }

    // ---- denominator: LSE_j(alpha_j), alpha valid on q==0 lanes only ----
    float a = (q == 0) ? ((float)m_int * 0.69314718055994531f + logf(pcur))
                       : -INFINITY;
    float v = a;
#pragma unroll
    for (int o = 1; o < 64; o <<= 1) v = fmaxf(v, __shfl_xor(v, o));
    if ((tid & 63) == 0) scratch[tid >> 6] = v;
    __syncthreads();
    float mx = fmaxf(fmaxf(scratch[0], scratch[1]), fmaxf(scratch[2], scratch[3]));
    float ev = (q == 0) ? __expf(a - mx) : 0.0f;
#pragma unroll
    for (int o = 1; o < 64; o <<= 1) ev += __shfl_xor(ev, o);
    __syncthreads();
    if ((tid & 63) == 0) scratch[tid >> 6] = ev;
    __syncthreads();
    float den = mx + logf((scratch[0] + scratch[1]) + (scratch[2] + scratch[3]));

    // ---- numerator (gold-path score) ----
    float numpart = 0.0f, maskpart = 0.0f;
#pragma unroll
    for (int kk = 0; kk < TT / 256; ++kk) {
        int t = tid + 256 * kk;
        int tg = btags[t];
        float mf = (float)bmask[t];
        maskpart += mf;
        if (t < TT - 1) {
            int tg1   = btags[t + 1];
            float mf1 = (float)bmask[t + 1];
            numpart += trans[tg * KK + tg1] * mf1;
            numpart += binp[(size_t)t * KK + tg] * mf;
        }
    }
#pragma unroll
    for (int o = 1; o < 64; o <<= 1) numpart += __shfl_xor(numpart, o);
#pragma unroll
    for (int o = 1; o < 64; o <<= 1) maskpart += __shfl_xor(maskpart, o);
    __syncthreads();
    if ((tid & 63) == 0) {
        scratch[tid >> 6]       = numpart;
        scratch[4 + (tid >> 6)] = maskpart;
    }
    __syncthreads();
    if (tid == 0) {
        float num  = (scratch[0] + scratch[1]) + (scratch[2] + scratch[3]);
        float msum = (scratch[4] + scratch[5]) + (scratch[6] + scratch[7]);
        int last_idx = (int)msum - 1;
        int ltag = btags[last_idx];
        num += binp[(size_t)(TT - 1) * KK + ltag] * (float)bmask[TT - 1];
        atomicAdd(out, num - den);
    }
}

extern "C" void kernel_launch(void* const* d_in, const int* in_sizes, int n_in,
                              void* d_out, int out_size, void* d_ws, size_t ws_size,
                              hipStream_t stream) {
    const float* inputs = (const float*)d_in[0];
    const float* trans  = (const float*)d_in[1];
    const int* tagsp    = (const int*)d_in[2];
    const int* maskp    = (const int*)d_in[3];
    float* out          = (float*)d_out;
    zero_out_kernel<<<1, 1, 0, stream>>>(out);
    crf_kernel<<<BB, 256, 0, stream>>>(inputs, trans, tagsp, maskp, out);
}

// Round 4
// 661.272 us; speedup vs baseline: 1.2338x; 1.0898x over previous
//
#include <hip/hip_runtime.h>
#include <math.h>

#define BB 256
#define TT 1024
#define KK 128
#define CHUNK 8
#define NCHUNK (TT / CHUNK)  // 128
#define PSTRIDE 160          // ushort stride of one p buffer; q-half at +80 (160 B)

__global__ void zero_out_kernel(float* out) { out[0] = 0.0f; }

#define LOBF(u) __uint_as_float((u) << 16)
#define HIBF(u) __uint_as_float((u) & 0xFFFF0000u)

// E init: V gets exp(trans[I0..I0+3][j]) (column j, rows I0..)
#define LDE(V, I0) { V.x = expf(tcol[(size_t)(I0) * KK]); \
                     V.y = expf(tcol[(size_t)((I0) + 1) * KK]); \
                     V.z = expf(tcol[(size_t)((I0) + 2) * KK]); \
                     V.w = expf(tcol[(size_t)((I0) + 3) * KK]); }

// 8 bf16 p-values in uint4 V against 8 E values in EA,EB
#define FMA8(V, EA, EB) { \
    z0 = fmaf(LOBF(V.x), EA.x, z0); z1 = fmaf(HIBF(V.x), EA.y, z1); \
    z2 = fmaf(LOBF(V.y), EA.z, z2); z3 = fmaf(HIBF(V.y), EA.w, z3); \
    z0 = fmaf(LOBF(V.z), EB.x, z0); z1 = fmaf(HIBF(V.z), EB.y, z1); \
    z2 = fmaf(LOBF(V.w), EB.z, z2); z3 = fmaf(HIBF(V.w), EB.w, z3); }

// One block per batch. 256 threads: j = tid>>1 (output state), q = tid&1 (i-half).
// Forward recursion in exp space; p stored bf16 in LDS (halves LDS-pipe cycles),
// E = exp(trans) in 16 NAMED float4 registers (spill-proof), X = exp(emit) in LDS.
// Renorm by exact power-of-2 from bf16 p_prev[0]'s exponent (lag-0 via broadcast read).
__global__ __launch_bounds__(256, 1) void crf_kernel(
    const float* __restrict__ inputs,      // B*T*K fp32
    const float* __restrict__ trans,       // K*K fp32
    const int* __restrict__ tags,          // B*T int32 view
    const int* __restrict__ mask,          // B*T int32
    float* __restrict__ out)               // scalar
{
    __shared__ __align__(16) unsigned short pbuf[2][PSTRIDE];  // bf16 p, q-halves 160B apart
    __shared__ __align__(16) float ebuf[2][CHUNK * KK];        // exp(emissions)
    __shared__ float mbuf[2][CHUNK];
    __shared__ float scratch[8];

    const int tid = threadIdx.x;
    const int q   = tid & 1;
    const int j   = tid >> 1;
    const int b   = blockIdx.x;

    const float* binp = inputs + (size_t)b * TT * KK;
    const int* bmask  = mask + (size_t)b * TT;
    const int* btags  = tags + (size_t)b * TT;

    // ---- E in 16 named float4s: i = q*64 + 8*blk + {0..7} -> (Eka, Ekb) ----
    const float* tcol = trans + j;
    const int ib = q * 64;
    float4 E0a, E0b, E1a, E1b, E2a, E2b, E3a, E3b, E4a, E4b, E5a, E5b, E6a, E6b, E7a, E7b;
    LDE(E0a, ib + 0)  LDE(E0b, ib + 4)
    LDE(E1a, ib + 8)  LDE(E1b, ib + 12)
    LDE(E2a, ib + 16) LDE(E2b, ib + 20)
    LDE(E3a, ib + 24) LDE(E3b, ib + 28)
    LDE(E4a, ib + 32) LDE(E4b, ib + 36)
    LDE(E5a, ib + 40) LDE(E5b, ib + 44)
    LDE(E6a, ib + 48) LDE(E6b, ib + 52)
    LDE(E7a, ib + 56) LDE(E7b, ib + 60)

    // ---- stage chunk 0 of emissions as X = exp(e), + mask ----
    {
        float4 e4 = ((const float4*)binp)[tid];
        e4.x = __expf(e4.x); e4.y = __expf(e4.y);
        e4.z = __expf(e4.z); e4.w = __expf(e4.w);
        ((float4*)ebuf[0])[tid] = e4;
    }
    if (tid < CHUNK) mbuf[0][tid] = (float)bmask[tid];
    __syncthreads();

    // ---- t = 0: p = exp(alpha0) = X[0][j], m = 0 ----
    float pcur = ebuf[0][j];
    int m_int = 0;
    if (q == 0) {
        unsigned bits = __float_as_uint(pcur);
        unsigned r = (bits + 0x7FFFu + ((bits >> 16) & 1u)) >> 16;   // RNE to bf16
        pbuf[0][(j & 63) + ((j >> 6) * 80)] = (unsigned short)r;
    }
    __syncthreads();

    for (int c = 0; c < NCHUNK; ++c) {
        // prefetch next emission chunk into registers (raw e; exp applied at store)
        float4 epre; int mpre = 0;
        if (c + 1 < NCHUNK) {
            epre = ((const float4*)(binp + (size_t)(c + 1) * CHUNK * KK))[tid];
            if (tid < CHUNK) mpre = bmask[(c + 1) * CHUNK + tid];
        }
        const float* eb = ebuf[c & 1];
        const float* mb = mbuf[c & 1];
        const int s0 = (c == 0) ? 1 : 0;
        for (int s = s0; s < CHUNK; ++s) {
            const int t = c * CHUNK + s;
            const uint4* pr4 = (const uint4*)(pbuf[(t - 1) & 1] + q * 80);
            uint4 v0 = pr4[0], v1 = pr4[1], v2 = pr4[2], v3 = pr4[3];
            uint4 v4 = pr4[4], v5 = pr4[5], v6 = pr4[6], v7 = pr4[7];
            float z0 = 0.f, z1 = 0.f, z2 = 0.f, z3 = 0.f;
            FMA8(v0, E0a, E0b) FMA8(v1, E1a, E1b)
            FMA8(v2, E2a, E2b) FMA8(v3, E3a, E3b)
            FMA8(v4, E4a, E4b) FMA8(v5, E5a, E5b)
            FMA8(v6, E6a, E6b) FMA8(v7, E7a, E7b)
            float z = (z0 + z1) + (z2 + z3);
            z += __shfl_xor(z, 1);                 // combine the two i-halves
            float X  = eb[s * KK + j];
            float mi = mb[s];
            float pn = (mi != 0.0f) ? z * X : pcur;   // mask-hold (mi in {0,1})
            // renorm: exact pow2 from bf16 p_prev[q*64]'s exponent (q0 chain is canonical)
            unsigned u0 = v0.x << 16;
            int E0 = (int)((u0 >> 23) & 255u) - 127;
            float sc = __uint_as_float((unsigned)(127 - E0) << 23);   // 2^-E0
            pcur = pn * sc;
            m_int += E0;
            if (q == 0) {
                unsigned bits = __float_as_uint(pcur);
                unsigned r = (bits + 0x7FFFu + ((bits >> 16) & 1u)) >> 16;
                pbuf[t & 1][(j & 63) + ((j >> 6) * 80)] = (unsigned short)r;
            }
            __syncthreads();
        }
        if (c + 1 < NCHUNK) {
            epre.x = __expf(epre.x); epre.y = __expf(epre.y);
            epre.z = __expf(epre.z); epre.w = __expf(epre.w);
            ((float4*)ebuf[(c + 1) & 1])[tid] = epre;
            if (tid < CHUNK) mbuf[(c + 1) & 1][tid] = (float)mpre;
            __syncthreads();
        }
    }

    // ---- denominator: LSE_j(alpha_j); alpha valid on q==0 lanes only ----
    float a = (q == 0) ? ((float)m_int * 0.69314718055994531f + logf(pcur))
                       : -INFINITY;
    float v = a;
#pragma unroll
    for (int o = 1; o < 64; o <<= 1) v = fmaxf(v, __shfl_xor(v, o));
    if ((tid & 63) == 0) scratch[tid >> 6] = v;
    __syncthreads();
    float mx = fmaxf(fmaxf(scratch[0], scratch[1]), fmaxf(scratch[2], scratch[3]));
    float ev = (q == 0) ? __expf(a - mx) : 0.0f;
#pragma unroll
    for (int o = 1; o < 64; o <<= 1) ev += __shfl_xor(ev, o);
    __syncthreads();
    if ((tid & 63) == 0) scratch[tid >> 6] = ev;
    __syncthreads();
    float den = mx + logf((scratch[0] + scratch[1]) + (scratch[2] + scratch[3]));

    // ---- numerator (gold-path score) ----
    float numpart = 0.0f, maskpart = 0.0f;
#pragma unroll
    for (int kk = 0; kk < TT / 256; ++kk) {
        int t = tid + 256 * kk;
        int tg = btags[t];
        float mf = (float)bmask[t];
        maskpart += mf;
        if (t < TT - 1) {
            int tg1   = btags[t + 1];
            float mf1 = (float)bmask[t + 1];
            numpart += trans[tg * KK + tg1] * mf1;
            numpart += binp[(size_t)t * KK + tg] * mf;
        }
    }
#pragma unroll
    for (int o = 1; o < 64; o <<= 1) numpart += __shfl_xor(numpart, o);
#pragma unroll
    for (int o = 1; o < 64; o <<= 1) maskpart += __shfl_xor(maskpart, o);
    __syncthreads();
    if ((tid & 63) == 0) {
        scratch[tid >> 6]       = numpart;
        scratch[4 + (tid >> 6)] = maskpart;
    }
    __syncthreads();
    if (tid == 0) {
        float num  = (scratch[0] + scratch[1]) + (scratch[2] + scratch[3]);
        float msum = (scratch[4] + scratch[5]) + (scratch[6] + scratch[7]);
        int last_idx = (int)msum - 1;
        int ltag = btags[last_idx];
        num += binp[(size_t)(TT - 1) * KK + ltag] * (float)bmask[TT - 1];
        atomicAdd(out, num - den);
    }
}

extern "C" void kernel_launch(void* const* d_in, const int* in_sizes, int n_in,
                              void* d_out, int out_size, void* d_ws, size_t ws_size,
                              hipStream_t stream) {
    const float* inputs = (const float*)d_in[0];
    const float* trans  = (const float*)d_in[1];
    const int* tagsp    = (const int*)d_in[2];
    const int* maskp    = (const int*)d_in[3];
    float* out          = (float*)d_out;
    zero_out_kernel<<<1, 1, 0, stream>>>(out);
    crf_kernel<<<BB, 256, 0, stream>>>(inputs, trans, tagsp, maskp, out);
}